// Round 10
// baseline (152.065 us; speedup 1.0000x reference)
//
#include <hip/hip_runtime.h>

// LIF net on MI355X.  R10: A-operand direct-to-register GEMM (no A LDS).
//  1. convert_W: Bt[25][256][32] bf16 (relu, slot-swizzled, K-pad 800) + wrelu
//  2. gemm_hidden: 512 blocks (b, t-quarter), tile 128m x 256n, BK=32.
//     A-frags loaded per-lane straight from spikes (m=t => coalesced),
//     cvt+pack in reg; only W tile staged in LDS (16KB dbuf, gload16);
//     ONE __syncthreads per K-step.  Epilogue transpose -> Ih[b][h][512].
//  3. scan_h: wave-per-row parallel LIF scan (shfl_up affine composition)
//  4. out_fused: per-b VALU dot (K=256,N=10) -> LDS -> segmented v_o scan
// ws: wrelu @0 (10KB) | Bt @16KB (400KB) | Ih @512KB (33.55MB)

typedef __attribute__((ext_vector_type(4))) float  floatx4;
typedef __attribute__((ext_vector_type(8))) short  shortx8;
typedef unsigned short u16;
typedef unsigned int   u32;

#define B_   128
#define NIN  784
#define NH   256
#define NO   10
#define T_   500
#define NK   25            // K padded to 800, slabs of 32

__device__ __forceinline__ u16 f2bf(float f) {
    union { float f; u32 u; } x; x.f = f;
    u32 r = x.u + 0x7FFFu + ((x.u >> 16) & 1u);   // RNE
    return (u16)(r >> 16);
}
__device__ __forceinline__ float bf2f(u16 u) {
    union { u32 u; float f; } x; x.u = ((u32)u) << 16; return x.f;
}
__device__ __forceinline__ float sigmoid5(float v) {
    return 1.0f / (1.0f + __expf(-5.0f * (v - 1.0f)));
}

__device__ __forceinline__ void gload16(const u16* g, u16* l) {
    __builtin_amdgcn_global_load_lds(
        (const __attribute__((address_space(1))) unsigned int*)(const void*)g,
        (__attribute__((address_space(3))) unsigned int*)(void*)l, 16, 0, 0);
}

// ---------- Pre-pass: Bt[kt][n][slot*8 + k&7] bf16 + wrelu ----------
__global__ void convert_W(const float* __restrict__ w_ih,
                          const float* __restrict__ w_ho,
                          u16* __restrict__ Bt, float* __restrict__ wrelu) {
    if (blockIdx.x == NK * 32) {
        for (int i = threadIdx.x; i < NH * NO; i += 256)
            wrelu[i] = fmaxf(0.f, w_ho[i]);
        return;
    }
    const int k = blockIdx.x;           // 0..799
    const int n = threadIdx.x;          // 0..255
    const float f = (k < NIN) ? fmaxf(0.f, w_ih[k * NH + n]) : 0.f;
    const int kt = k >> 5, kk = k & 31;
    const int slot = (kk >> 3) ^ (n & 3) ^ ((n >> 2) & 3);
    Bt[(size_t)kt * 8192 + n * 32 + slot * 8 + (kk & 7)] = f2bf(f);
}

// ---------- hidden GEMM: A direct-to-reg, W-only LDS ----------
// 512 blocks = (b, tq); 512 thr = 8 waves (2 wm x 4 wn), wave tile 64x64
// (4x4 frags, 64 acc VGPR).  LDS 32KB: Bs dbuf 2x16KB (epilogue Cs reuse).
__global__ __launch_bounds__(512, 4) void gemm_hidden(
    const float* __restrict__ spikes,   // [128][784][500] f32
    const u16* __restrict__ Bt,         // [25][256][32] bf16 swizzled
    u16* __restrict__ Ih)               // [128][256][512] bf16
{
    __shared__ u16 SH[16384];           // 32KB
    u16* BS0 = SH;                      // 8192 u16 = 16KB
    u16* BS1 = SH + 8192;

    const int tid = threadIdx.x;
    const int b   = blockIdx.x >> 2;
    const int tq  = blockIdx.x & 3;
    const int t0  = tq * 128;

    const int lane = tid & 63, wid = tid >> 6;
    const int wm = wid >> 2, wn = wid & 3;             // wm 0..1, wn 0..3
    const int lg = lane >> 4, lr = lane & 15;

    const float* sb = spikes + (size_t)b * (NIN * T_);

    // per-frag t coordinate (m-role = t); guards only bite at tq=3,wm=1,mi=3
    int  tmi[4]; bool tok[4];
#pragma unroll
    for (int mi = 0; mi < 4; ++mi) {
        tmi[mi] = t0 + wm * 64 + mi * 16 + lr;
        tok[mi] = (tmi[mi] < T_);
    }

    int bOff[4];
#pragma unroll
    for (int ni = 0; ni < 4; ++ni) {
        const int n = wn * 64 + ni * 16 + lr;
        bOff[ni] = n * 32 + ((lg ^ (n & 3) ^ ((n >> 2) & 3)) << 3);
    }

    floatx4 acc[4][4];
#pragma unroll
    for (int i = 0; i < 4; ++i)
#pragma unroll
        for (int j = 0; j < 4; ++j) acc[i][j] = (floatx4)0.f;

#define STAGEB(BSX, itv) { const u16* src = Bt + (size_t)(itv) * 8192;         \
        gload16(src + tid * 8,        (BSX) + tid * 8);                        \
        gload16(src + 4096 + tid * 8, (BSX) + 4096 + tid * 8); }

    // prologue: W0 in flight; first barrier drains it
    STAGEB(BS0, 0);
    __syncthreads();

    for (int it = 0; it < NK; ++it) {
        u16* cur = (it & 1) ? BS1 : BS0;
        u16* nxt = (it & 1) ? BS0 : BS1;
        if (it + 1 < NK) STAGEB(nxt, it + 1);

        // ---- A-frags: 8 guarded dword loads + cvt/pack, per mi ----
        const int kb = it * 32 + lg * 8;
        shortx8 af[4];
#pragma unroll
        for (int mi = 0; mi < 4; ++mi) {
            float rw[8];
#pragma unroll
            for (int j = 0; j < 8; ++j) {
                const bool ok = tok[mi] && (kb + j < NIN);
                const float* p = ok ? (sb + (size_t)(kb + j) * T_ + tmi[mi]) : sb;
                const float v = *p;
                rw[j] = ok ? v : 0.f;
            }
            union { shortx8 s; u32 w[4]; } u;
#pragma unroll
            for (int q = 0; q < 4; ++q)
                u.w[q] = (u32)f2bf(rw[2 * q]) | ((u32)f2bf(rw[2 * q + 1]) << 16);
            af[mi] = u.s;
        }

        // ---- B-frags from LDS + MFMA ----
        shortx8 bf[4];
#pragma unroll
        for (int ni = 0; ni < 4; ++ni)
            bf[ni] = *(const shortx8*)&cur[bOff[ni]];
#pragma unroll
        for (int mi = 0; mi < 4; ++mi)
#pragma unroll
            for (int ni = 0; ni < 4; ++ni)
                acc[mi][ni] = __builtin_amdgcn_mfma_f32_16x16x32_bf16(
                    af[mi], bf[ni], acc[mi][ni], 0, 0, 0);

        __syncthreads();   // drains W(nxt) gloads + my ds_reads of cur
    }

    // epilogue: two m-halves via Cs[256][64] (32KB) -> Ih[b][n][t0 + h*64 + m]
    u16* Cs = SH;
#pragma unroll
    for (int h = 0; h < 2; ++h) {
        if (wm == h) {
#pragma unroll
            for (int mi = 0; mi < 4; ++mi)
#pragma unroll
                for (int rr = 0; rr < 2; ++rr) {
                    const int mloc = mi * 16 + lg * 4 + rr * 2;
#pragma unroll
                    for (int ni = 0; ni < 4; ++ni) {
                        const int n = wn * 64 + ni * 16 + lr;
                        const u32 pk = (u32)f2bf(acc[mi][ni][rr * 2]) |
                                       ((u32)f2bf(acc[mi][ni][rr * 2 + 1]) << 16);
                        *(u32*)&Cs[n * 64 + (mloc ^ ((n & 7) << 3))] = pk;
                    }
                }
        }
        __syncthreads();
        {
            const int n = tid >> 1, mh = tid & 1;
            u16* gdst = Ih + ((size_t)b * 256 + n) * 512 + t0 + h * 64 + mh * 32;
#pragma unroll
            for (int j = 0; j < 4; ++j) {
                const uint4 v = *(const uint4*)&Cs[n * 64 + ((mh * 32 + 8 * j) ^ ((n & 7) << 3))];
                *(uint4*)(gdst + 8 * j) = v;
            }
        }
        __syncthreads();
    }
#undef STAGEB
}

// ---------- parallel hidden LIF scan (in place) ----------
__global__ __launch_bounds__(512) void scan_h(u16* __restrict__ Ih) {
    const int lane = threadIdx.x & 63;
    const int row  = blockIdx.x * 8 + (threadIdx.x >> 6);
    u16* p = Ih + (size_t)row * 512 + lane * 8;
    shortx8 xv = *(const shortx8*)p;
    float I[8];
#pragma unroll
    for (int j = 0; j < 8; ++j) I[j] = bf2f((u16)xv[j]);
    float z = 0.f;
#pragma unroll
    for (int j = 0; j < 8; ++j) z += (I[j] - z) * 0.1f;
    float A = 0.43046721f, Bv = z;                 // 0.9^8
#pragma unroll
    for (int d = 1; d < 64; d <<= 1) {
        const float Au = __shfl_up(A, d);
        const float Bu = __shfl_up(Bv, d);
        if (lane >= d) { Bv = fmaf(A, Bu, Bv); A *= Au; }
    }
    float v = __shfl_up(Bv, 1);
    if (lane == 0) v = 0.f;
#pragma unroll
    for (int j = 0; j < 8; ++j) {
        v += (I[j] - v) * 0.1f;
        xv[j] = (short)f2bf(sigmoid5(v));
    }
    *(shortx8*)p = xv;
}

// ---------- output dot + segmented v_o scan ----------
__global__ __launch_bounds__(512) void out_fused(
    const u16* __restrict__ s,          // [128][256][512] bf16
    const float* __restrict__ wr,       // [256][10] relu'd f32
    float* __restrict__ out)
{
    __shared__ float Io[T_ * NO];
    __shared__ float vend[25][NO], vstart[25][NO], psum[25][NO];
    const int b = blockIdx.x, tid = threadIdx.x;

    float acc[NO];
#pragma unroll
    for (int o = 0; o < NO; ++o) acc[o] = 0.f;
    const u16* sb = s + (size_t)b * NH * 512 + tid;
#pragma unroll 2
    for (int h = 0; h < NH; ++h) {
        const float sv = bf2f(sb[h * 512]);
#pragma unroll
        for (int o = 0; o < NO; ++o) acc[o] = fmaf(sv, wr[h * NO + o], acc[o]);
    }
    if (tid < T_) {
#pragma unroll
        for (int o = 0; o < NO; ++o) Io[tid * NO + o] = acc[o];
    }
    __syncthreads();

    const int seg = tid / NO, o = tid - seg * NO;
    if (tid < 250) {
        float v = 0.f;
#pragma unroll
        for (int j = 0; j < 20; ++j)
            v += (Io[(seg * 20 + j) * NO + o] - v) * 0.1f;
        vend[seg][o] = v;
    }
    __syncthreads();
    if (tid < NO) {
        float vs = 0.f;
#pragma unroll
        for (int sg = 0; sg < 25; ++sg) {
            vstart[sg][tid] = vs;
            vs = vend[sg][tid] + 0.12157665459f * vs;   // 0.9^20
        }
    }
    __syncthreads();
    if (tid < 250) {
        float v = vstart[seg][o], ps = 0.f;
#pragma unroll
        for (int j = 0; j < 20; ++j) {
            const int t = seg * 20 + j;
            v += (Io[t * NO + o] - v) * 0.1f;
            const float sv = sigmoid5(v);
            out[(size_t)b * (NO * T_) + (size_t)o * T_ + t] = sv;
            ps += sv;
        }
        psum[seg][o] = ps;
    }
    __syncthreads();
    if (tid < NO) {
        float tot = 0.f;
#pragma unroll
        for (int sg = 0; sg < 25; ++sg) tot += psum[sg][tid];
        out[(size_t)(B_ * NO) * T_ + b * NO + tid] = tot * (1.0f / T_);
    }
}

extern "C" void kernel_launch(void* const* d_in, const int* in_sizes, int n_in,
                              void* d_out, int out_size, void* d_ws, size_t ws_size,
                              hipStream_t stream) {
    (void)in_sizes; (void)n_in; (void)out_size; (void)ws_size;
    const float* spikes = (const float*)d_in[0];   // [128][784][500]
    const float* w_ih   = (const float*)d_in[1];   // [784][256]
    const float* w_ho   = (const float*)d_in[2];   // [256][10]
    float* out = (float*)d_out;

    float* wrelu = (float*)d_ws;                            // 10KB @0
    u16*   Bt    = (u16*)((char*)d_ws + 16384);             // 400KB
    u16*   Ih    = (u16*)((char*)d_ws + 524288);            // 33.55MB

    convert_W  <<<NK * 32 + 1, 256, 0, stream>>>(w_ih, w_ho, Bt, wrelu);
    gemm_hidden<<<512, 512, 0, stream>>>(spikes, Bt, Ih);
    scan_h     <<<4096, 512, 0, stream>>>(Ih);
    out_fused  <<<B_, 512, 0, stream>>>(Ih, wrelu, out);
}

// Round 11
// 119.951 us; speedup vs baseline: 1.2677x; 1.2677x over previous
//
#include <hip/hip_runtime.h>

// LIF net on MI355X.  R11 = R9 minus barrier-drain:
//  - B: per-thread register prefetch from linear L2-resident Bt (no gload_lds)
//  - barriers: lgkmcnt(0)+s_barrier only -> A/B loads survive barriers,
//    compiler emits counted vmcnt at consumption points.
//  1. convert_W: Bt[25][256][32] bf16 linear (relu, K-pad 800) + wrelu f32
//  2. gemm_hidden: 512 blocks (b, tq), tile 128m x 256n, BK=32, A slot-
//     swizzled LDS dbuf (16KB) -> Ih[b][h][512] bf16 (transposed epilogue)
//  3. scan_h: wave-per-row parallel LIF scan (shfl_up affine composition)
//  4. out_fused: per-b VALU dot (K=256,N=10) -> LDS -> segmented v_o scan
// ws: wrelu @0 (10KB) | Bt @16KB (400KB) | Ih @512KB (33.55MB)

typedef __attribute__((ext_vector_type(4))) float  floatx4;
typedef __attribute__((ext_vector_type(8))) short  shortx8;
typedef unsigned short u16;
typedef unsigned int   u32;

#define B_   128
#define NIN  784
#define NH   256
#define NO   10
#define T_   500
#define NK   25            // K padded to 800, tiles of 32

__device__ __forceinline__ u16 f2bf(float f) {
    union { float f; u32 u; } x; x.f = f;
    u32 r = x.u + 0x7FFFu + ((x.u >> 16) & 1u);   // RNE
    return (u16)(r >> 16);
}
__device__ __forceinline__ float bf2f(u16 u) {
    union { u32 u; float f; } x; x.u = ((u32)u) << 16; return x.f;
}
__device__ __forceinline__ float sigmoid5(float v) {
    return 1.0f / (1.0f + __expf(-5.0f * (v - 1.0f)));
}

// LDS-only barrier: ds ops drained, vmem loads stay in flight
#define BARRIER { asm volatile("s_waitcnt lgkmcnt(0)" ::: "memory");           \
                  __builtin_amdgcn_s_barrier(); }

// ---------- Pre-pass: Bt[kt][n][kk] bf16 linear (relu, padded) + wrelu ----------
__global__ void convert_W(const float* __restrict__ w_ih,
                          const float* __restrict__ w_ho,
                          u16* __restrict__ Bt, float* __restrict__ wrelu) {
    if (blockIdx.x == NK * 32) {
        for (int i = threadIdx.x; i < NH * NO; i += 256)
            wrelu[i] = fmaxf(0.f, w_ho[i]);
        return;
    }
    const int k = blockIdx.x;           // 0..799
    const int n = threadIdx.x;          // 0..255
    const float f = (k < NIN) ? fmaxf(0.f, w_ih[k * NH + n]) : 0.f;
    const int kt = k >> 5, kk = k & 31;
    Bt[(size_t)kt * 8192 + n * 32 + kk] = f2bf(f);
}

// ---------- hidden GEMM ----------
// 512 blocks = (b, tq); 512 thr = 8 waves (2 wm x 4 wn), wave tile 64x64
// (4x4 frags, 64 acc VGPR).  LDS 32KB: As dbuf 2x8KB (+Cs epilogue reuse).
__global__ __launch_bounds__(512, 4) void gemm_hidden(
    const float* __restrict__ spikes,   // [128][784][500] f32
    const u16* __restrict__ Bt,         // [25][256][32] bf16 linear
    u16* __restrict__ Ih)               // [128][256][512] bf16
{
    __shared__ u16 SH[16384];           // 32KB
    u16* AS0 = SH;                      // 4096 u16 = 8KB
    u16* AS1 = SH + 4096;

    const int tid = threadIdx.x;
    const int b   = blockIdx.x >> 2;
    const int tq  = blockIdx.x & 3;
    const int t0  = tq * 128;

    // A staging role: thread = (kp 0..15, tg 0..31): k = 2kp,2kp+1, t = t0+tg*4
    const int kp = tid >> 5, tg = tid & 31;
    const int tloc = t0 + tg * 4;
    const int koff = (2 * kp) & 7;
    const int oct  = kp >> 2;
    const bool t_ok = (tloc <= 496);
    const float* sbase = spikes + (size_t)b * (NIN * T_) + tloc;

    // MFMA roles
    const int lane = tid & 63, wid = tid >> 6;
    const int wm = wid >> 2, wn = wid & 3;             // wm 0..1, wn 0..3
    const int lg = lane >> 4, lr = lane & 15;
    int aOff[4], bOff[4];
#pragma unroll
    for (int mi = 0; mi < 4; ++mi) {
        const int m = wm * 64 + mi * 16 + lr;
        aOff[mi] = m * 32 + ((lg ^ (m & 3) ^ ((m >> 2) & 3)) << 3);
    }
#pragma unroll
    for (int ni = 0; ni < 4; ++ni)
        bOff[ni] = (wn * 64 + ni * 16 + lr) * 32 + lg * 8;   // linear Bt frag

    floatx4 acc[4][4];
#pragma unroll
    for (int i = 0; i < 4; ++i)
#pragma unroll
        for (int j = 0; j < 4; ++j) acc[i][j] = (floatx4)0.f;

#define LOADA(v0, v1, itv) {                                                   \
        const int gk = (itv) * 32 + 2 * kp;                                    \
        const bool ok0 = t_ok && (gk < NIN);                                   \
        const bool ok1 = t_ok && (gk + 1 < NIN);                               \
        const float* p0 = ok0 ? (sbase + (size_t)gk * T_) : sbase;             \
        const float* p1 = ok1 ? (sbase + (size_t)(gk + 1) * T_) : sbase;       \
        floatx4 u0 = *(const floatx4*)p0;                                      \
        floatx4 u1 = *(const floatx4*)p1;                                      \
        v0 = ok0 ? u0 : (floatx4)0.f;                                          \
        v1 = ok1 ? u1 : (floatx4)0.f; }

#define WRITEA(ASX, v0, v1) { _Pragma("unroll") for (int j = 0; j < 4; ++j) {  \
        const int m = tg * 4 + j;                                              \
        const int slot = oct ^ (m & 3) ^ ((m >> 2) & 3);                       \
        const u32 pk = (u32)f2bf(v0[j]) | ((u32)f2bf(v1[j]) << 16);            \
        *(u32*)&(ASX)[m * 32 + slot * 8 + koff] = pk; } }

#define LOADB(bfv, itv) { const u16* src = Bt + (size_t)(itv) * 8192;          \
        _Pragma("unroll") for (int ni = 0; ni < 4; ++ni)                       \
            bfv[ni] = *(const shortx8*)(src + bOff[ni]); }

#define MFMAIT(ASX, bfv) { shortx8 af[4];                                      \
        _Pragma("unroll") for (int mi = 0; mi < 4; ++mi)                       \
            af[mi] = *(const shortx8*)&(ASX)[aOff[mi]];                        \
        _Pragma("unroll") for (int mi = 0; mi < 4; ++mi)                       \
        _Pragma("unroll") for (int ni = 0; ni < 4; ++ni)                       \
            acc[mi][ni] = __builtin_amdgcn_mfma_f32_16x16x32_bf16(             \
                af[mi], bfv[ni], acc[mi][ni], 0, 0, 0); }

    floatx4 vaP0, vaP1;
    shortx8 bE[4], bO[4];

    // prologue: tile0 A+B, stage A0, prefetch A(tile1)
    LOADA(vaP0, vaP1, 0);
    LOADB(bE, 0);
    WRITEA(AS0, vaP0, vaP1);            // compiler: counted vmcnt for vaP only
    LOADA(vaP0, vaP1, 1);
    BARRIER;

    // body: iter it computes tile it; 2-unrolled for static buffer names
    for (int it = 0; it < 24; it += 2) {
        // even it: cur=AS0/bE, nxt=AS1/bO
        WRITEA(AS1, vaP0, vaP1);        // tile it+1
        LOADA(vaP0, vaP1, it + 2);
        LOADB(bO, it + 1);
        MFMAIT(AS0, bE);
        BARRIER;
        // odd it+1: cur=AS1/bO
        WRITEA(AS0, vaP0, vaP1);        // tile it+2
        LOADA(vaP0, vaP1, it + 3);      // itv<=25: clamps into Bt/ws pad, unused
        LOADB(bE, it + 2);
        MFMAIT(AS1, bO);
        BARRIER;
    }
    MFMAIT(AS0, bE);                    // tile 24
    BARRIER;                            // LDS reads done; SH free for Cs

    // epilogue: two m-halves via Cs[256][64] (32KB) -> Ih[b][n][t0 + h*64 + m]
    u16* Cs = SH;
#pragma unroll
    for (int h = 0; h < 2; ++h) {
        if (wm == h) {
#pragma unroll
            for (int mi = 0; mi < 4; ++mi)
#pragma unroll
                for (int rr = 0; rr < 2; ++rr) {
                    const int mloc = mi * 16 + lg * 4 + rr * 2;
#pragma unroll
                    for (int ni = 0; ni < 4; ++ni) {
                        const int n = wn * 64 + ni * 16 + lr;
                        const u32 pk = (u32)f2bf(acc[mi][ni][rr * 2]) |
                                       ((u32)f2bf(acc[mi][ni][rr * 2 + 1]) << 16);
                        *(u32*)&Cs[n * 64 + (mloc ^ ((n & 7) << 3))] = pk;
                    }
                }
        }
        BARRIER;
        {
            const int n = tid >> 1, mh = tid & 1;
            u16* gdst = Ih + ((size_t)b * 256 + n) * 512 + t0 + h * 64 + mh * 32;
#pragma unroll
            for (int j = 0; j < 4; ++j) {
                const uint4 v = *(const uint4*)&Cs[n * 64 + ((mh * 32 + 8 * j) ^ ((n & 7) << 3))];
                *(uint4*)(gdst + 8 * j) = v;
            }
        }
        BARRIER;
    }
#undef LOADA
#undef WRITEA
#undef LOADB
#undef MFMAIT
}

// ---------- parallel hidden LIF scan (in place) ----------
__global__ __launch_bounds__(512) void scan_h(u16* __restrict__ Ih) {
    const int lane = threadIdx.x & 63;
    const int row  = blockIdx.x * 8 + (threadIdx.x >> 6);
    u16* p = Ih + (size_t)row * 512 + lane * 8;
    shortx8 xv = *(const shortx8*)p;
    float I[8];
#pragma unroll
    for (int j = 0; j < 8; ++j) I[j] = bf2f((u16)xv[j]);
    float z = 0.f;
#pragma unroll
    for (int j = 0; j < 8; ++j) z += (I[j] - z) * 0.1f;
    float A = 0.43046721f, Bv = z;                 // 0.9^8
#pragma unroll
    for (int d = 1; d < 64; d <<= 1) {
        const float Au = __shfl_up(A, d);
        const float Bu = __shfl_up(Bv, d);
        if (lane >= d) { Bv = fmaf(A, Bu, Bv); A *= Au; }
    }
    float v = __shfl_up(Bv, 1);
    if (lane == 0) v = 0.f;
#pragma unroll
    for (int j = 0; j < 8; ++j) {
        v += (I[j] - v) * 0.1f;
        xv[j] = (short)f2bf(sigmoid5(v));
    }
    *(shortx8*)p = xv;
}

// ---------- output dot + segmented v_o scan ----------
__global__ __launch_bounds__(512) void out_fused(
    const u16* __restrict__ s,          // [128][256][512] bf16
    const float* __restrict__ wr,       // [256][10] relu'd f32
    float* __restrict__ out)
{
    __shared__ float Io[T_ * NO];
    __shared__ float vend[25][NO], vstart[25][NO], psum[25][NO];
    const int b = blockIdx.x, tid = threadIdx.x;

    float acc[NO];
#pragma unroll
    for (int o = 0; o < NO; ++o) acc[o] = 0.f;
    const u16* sb = s + (size_t)b * NH * 512 + tid;
#pragma unroll 2
    for (int h = 0; h < NH; ++h) {
        const float sv = bf2f(sb[h * 512]);
#pragma unroll
        for (int o = 0; o < NO; ++o) acc[o] = fmaf(sv, wr[h * NO + o], acc[o]);
    }
    if (tid < T_) {
#pragma unroll
        for (int o = 0; o < NO; ++o) Io[tid * NO + o] = acc[o];
    }
    __syncthreads();

    const int seg = tid / NO, o = tid - seg * NO;
    if (tid < 250) {
        float v = 0.f;
#pragma unroll
        for (int j = 0; j < 20; ++j)
            v += (Io[(seg * 20 + j) * NO + o] - v) * 0.1f;
        vend[seg][o] = v;
    }
    __syncthreads();
    if (tid < NO) {
        float vs = 0.f;
#pragma unroll
        for (int sg = 0; sg < 25; ++sg) {
            vstart[sg][tid] = vs;
            vs = vend[sg][tid] + 0.12157665459f * vs;   // 0.9^20
        }
    }
    __syncthreads();
    if (tid < 250) {
        float v = vstart[seg][o], ps = 0.f;
#pragma unroll
        for (int j = 0; j < 20; ++j) {
            const int t = seg * 20 + j;
            v += (Io[t * NO + o] - v) * 0.1f;
            const float sv = sigmoid5(v);
            out[(size_t)b * (NO * T_) + (size_t)o * T_ + t] = sv;
            ps += sv;
        }
        psum[seg][o] = ps;
    }
    __syncthreads();
    if (tid < NO) {
        float tot = 0.f;
#pragma unroll
        for (int sg = 0; sg < 25; ++sg) tot += psum[sg][tid];
        out[(size_t)(B_ * NO) * T_ + b * NO + tid] = tot * (1.0f / T_);
    }
}

extern "C" void kernel_launch(void* const* d_in, const int* in_sizes, int n_in,
                              void* d_out, int out_size, void* d_ws, size_t ws_size,
                              hipStream_t stream) {
    (void)in_sizes; (void)n_in; (void)out_size; (void)ws_size;
    const float* spikes = (const float*)d_in[0];   // [128][784][500]
    const float* w_ih   = (const float*)d_in[1];   // [784][256]
    const float* w_ho   = (const float*)d_in[2];   // [256][10]
    float* out = (float*)d_out;

    float* wrelu = (float*)d_ws;                            // 10KB @0
    u16*   Bt    = (u16*)((char*)d_ws + 16384);             // 400KB (+pad)
    u16*   Ih    = (u16*)((char*)d_ws + 524288);            // 33.55MB

    convert_W  <<<NK * 32 + 1, 256, 0, stream>>>(w_ih, w_ho, Bt, wrelu);
    gemm_hidden<<<512, 512, 0, stream>>>(spikes, Bt, Ih);
    scan_h     <<<4096, 512, 0, stream>>>(Ih);
    out_fused  <<<B_, 512, 0, stream>>>(Ih, wrelu, out);
}